// Round 11
// baseline (305.651 us; speedup 1.0000x reference)
//
#include <hip/hip_runtime.h>
#include <cstdint>
#include <cstddef>

typedef _Float16 f16;
typedef _Float16 f16x8 __attribute__((ext_vector_type(8)));
typedef _Float16 f16x4 __attribute__((ext_vector_type(4)));
typedef float    f32x4 __attribute__((ext_vector_type(4)));
typedef float    f32x16 __attribute__((ext_vector_type(16)));
typedef unsigned int uint2v __attribute__((ext_vector_type(2)));

#define MFMA16(a,b,c) __builtin_amdgcn_mfma_f32_16x16x32_f16(a, b, c, 0, 0, 0)
#define MFMA32(a,b,c) __builtin_amdgcn_mfma_f32_32x32x16_f16(a, b, c, 0, 0, 0)

static __device__ __forceinline__ void gload_lds16(const void* g, void* l) {
  __builtin_amdgcn_global_load_lds(
      (const __attribute__((address_space(1))) unsigned int*)g,
      (__attribute__((address_space(3))) unsigned int*)l, 16, 0, 0);
}

static __device__ __forceinline__ int pkh(float a, float b) {
  auto t = __builtin_amdgcn_cvt_pkrtz(a, b);   // __fp16 x2
  return __builtin_bit_cast(int, t);
}

static __device__ __forceinline__ float ex2(float x) {
  return __builtin_amdgcn_exp2f(x);
}

// v_permlane32_swap: returns {a', b'} with a' = [a_lo | b_lo], b' = [a_hi | b_hi]
static __device__ __forceinline__ uint2v pswap(int a, int b) {
  return __builtin_amdgcn_permlane32_swap((unsigned)a, (unsigned)b, false, false);
}
static __device__ __forceinline__ float xhalf_max(float x) {
  uint2v r = pswap(__builtin_bit_cast(int, x), __builtin_bit_cast(int, x));
  return fmaxf(__builtin_bit_cast(float, r.x), __builtin_bit_cast(float, r.y));
}
static __device__ __forceinline__ float f3(float a, float b, float c) {
  return fmaxf(fmaxf(a, b), c);    // fuses to v_max3_f32
}

// ---------------------------------------------------------------------------
// Mega prep kernel: f32->f16 cast of x, all 9 weight transposes, qkv bias.
static __device__ __forceinline__ void wtrans_blk(float (*tile)[33],
                                                  const float* __restrict__ W,
                                                  f16* __restrict__ Wt,
                                                  int K, int N, int gx,
                                                  float scale, int lb) {
  const int n0 = (lb % gx) * 32, k0 = (lb / gx) * 32;
  const int c = threadIdx.x & 31, r = threadIdx.x >> 5;  // r: 0..7
#pragma unroll
  for (int i = 0; i < 4; i++) {
    int row = r + i * 8;
    tile[row][c] = W[(size_t)(k0 + row) * N + n0 + c];
  }
  __syncthreads();
#pragma unroll
  for (int i = 0; i < 4; i++) {
    int row = r + i * 8;
    Wt[(size_t)(n0 + row) * K + k0 + c] = (f16)(tile[c][row] * scale);
  }
}

__global__ __launch_bounds__(256)
void prep_kernel(const float* __restrict__ x, f16* __restrict__ xb,
                 const float* __restrict__ pW1, f16* __restrict__ wtP1,
                 const float* __restrict__ pW2, f16* __restrict__ wtP2,
                 const float* __restrict__ Wq,  f16* __restrict__ wtQ,
                 const float* __restrict__ Wk,  f16* __restrict__ wtK,
                 const float* __restrict__ Wv,  f16* __restrict__ wtV,
                 const float* __restrict__ Wo,  f16* __restrict__ wtO,
                 const float* __restrict__ Wf1, f16* __restrict__ wtF1,
                 const float* __restrict__ Wf2, f16* __restrict__ wtF2,
                 const float* __restrict__ bq, const float* __restrict__ bk,
                 const float* __restrict__ bv, float* __restrict__ bqkv) {
  __shared__ float tile[32][33];
  int b = blockIdx.x;
  if (b < 4096) {                       // cast x -> f16
    int i = b * 256 + threadIdx.x;
    float4 v = ((const float4*)x)[i];
    f16x4 h;
    h[0] = (f16)v.x; h[1] = (f16)v.y; h[2] = (f16)v.z; h[3] = (f16)v.w;
    *(f16x4*)(xb + (size_t)i * 4) = h;
    return;
  }
  b -= 4096;
  if (b < 2048) { wtrans_blk(tile, pW1, wtP1, 1024, 2048, 64, 1.f, b); return; }
  b -= 2048;
  if (b < 2048) { wtrans_blk(tile, pW2, wtP2, 2048, 1024, 32, 1.f, b); return; }
  b -= 2048;
  if (b < 1024) { wtrans_blk(tile, Wq, wtQ, 1024, 1024, 32, 0.18033688f, b); return; }
  b -= 1024;
  if (b < 1024) { wtrans_blk(tile, Wk, wtK, 1024, 1024, 32, 1.f, b); return; }
  b -= 1024;
  if (b < 1024) { wtrans_blk(tile, Wv, wtV, 1024, 1024, 32, 1.f, b); return; }
  b -= 1024;
  if (b < 1024) { wtrans_blk(tile, Wo, wtO, 1024, 1024, 32, 1.f, b); return; }
  b -= 1024;
  if (b < 4096) { wtrans_blk(tile, Wf1, wtF1, 1024, 4096, 128, 1.f, b); return; }
  b -= 4096;
  if (b < 4096) { wtrans_blk(tile, Wf2, wtF2, 4096, 1024, 32, 1.f, b); return; }
  b -= 4096;
  {                                     // qkv bias (12 blocks)
    int i = b * 256 + threadIdx.x;
    if (i < 1024)       bqkv[i] = bq[i] * 0.18033688f;
    else if (i < 2048)  bqkv[i] = bk[i - 1024];
    else if (i < 3072)  bqkv[i] = bv[i - 2048];
  }
}

// ---------------------------------------------------------------------------
// GEMM: out = epilogue(A[M][K]_f16 @ W^T[N][K]_f16 + bias)
// MODE 1: relu + f16 store
// MODE 3: f16 store, except cols>=2048 stored transposed to vt[bh][64][2048]
template <int MODE, bool PF>
__global__ __launch_bounds__(256, 2)
void gemm_kernel(const f16* __restrict__ A, const f16* __restrict__ W,
                 const float* __restrict__ bias, void* __restrict__ out,
                 f16* __restrict__ vt, int N, int K, int gx) {
  constexpr int BUFS = PF ? 2 : 1;
  __shared__ __align__(16) f16 lsA[BUFS * 128 * 64];
  __shared__ __align__(16) f16 lsB[BUFS * 128 * 64];
  const int tid  = threadIdx.x;
  const int lane = tid & 63;
  const int wid  = tid >> 6;
  const int frow = lane & 15;
  const int kgrp = lane >> 4;
  const int wmBase = (wid >> 1) * 64;
  const int wnBase = (wid & 1) * 64;

  const int bid = blockIdx.x;
  const int xcd = bid & 7, slot = bid >> 3;
  const int bm = (xcd << 2) + slot / gx;
  const int bn = slot % gx;

  const f32x4 zero4 = {0.f, 0.f, 0.f, 0.f};
  f32x4 acc[4][4];
#pragma unroll
  for (int i = 0; i < 4; i++)
#pragma unroll
    for (int j = 0; j < 4; j++) acc[i][j] = zero4;

  const f16* aSrc[4]; int lOffA[4];
  const f16* bSrc[4];
#pragma unroll
  for (int i = 0; i < 4; i++) {
    int c_lin = i * 256 + wid * 64 + lane;       // chunk id (16B units)
    int row = c_lin >> 3;
    int ch  = (c_lin & 7) ^ (row & 7);           // inverse-swizzled source chunk
    aSrc[i] = A + (size_t)(bm * 128 + row) * K + ch * 8;
    bSrc[i] = W + (size_t)(bn * 128 + row) * K + ch * 8;
    lOffA[i] = (i * 256 + wid * 64) * 8;
  }

  auto compute = [&](const f16* la, const f16* lb) {
#pragma unroll
    for (int kk = 0; kk < 2; kk++) {
      f16x8 af[4], bf[4];
#pragma unroll
      for (int i = 0; i < 4; i++) {
        int row = wmBase + i * 16 + frow;
        af[i] = *(const f16x8*)&la[row * 64 + (((kk * 4 + kgrp) ^ (row & 7)) << 3)];
      }
#pragma unroll
      for (int j = 0; j < 4; j++) {
        int row = wnBase + j * 16 + frow;
        bf[j] = *(const f16x8*)&lb[row * 64 + (((kk * 4 + kgrp) ^ (row & 7)) << 3)];
      }
#pragma unroll
      for (int i = 0; i < 4; i++)
#pragma unroll
        for (int j = 0; j < 4; j++) acc[i][j] = MFMA16(af[i], bf[j], acc[i][j]);
    }
  };

  const int nk = K >> 6;
  if constexpr (PF) {
#define GST(T, PB)                                                        \
    {                                                                     \
      f16* la = lsA + (PB) * 8192;                                        \
      f16* lb = lsB + (PB) * 8192;                                        \
      _Pragma("unroll") for (int i = 0; i < 4; i++) {                     \
        gload_lds16(aSrc[i] + (size_t)(T) * 64, la + lOffA[i]);           \
        gload_lds16(bSrc[i] + (size_t)(T) * 64, lb + lOffA[i]);           \
      }                                                                   \
    }
    GST(0, 0);
    for (int ks = 0; ks < nk; ++ks) {
      const int nt = (ks + 1 < nk) ? ks + 1 : nk - 1;   // dup-stage last tile
      GST(nt, (ks + 1) & 1);
      asm volatile("s_waitcnt vmcnt(8)" ::: "memory");  // tile ks landed
      __builtin_amdgcn_s_barrier();
      compute(lsA + (ks & 1) * 8192, lsB + (ks & 1) * 8192);
      __builtin_amdgcn_s_barrier();                     // buf free for ks+2
    }
    asm volatile("s_waitcnt vmcnt(0)" ::: "memory");    // drain dup-stage
#undef GST
  } else {
    for (int ks = 0; ks < nk; ++ks) {
#pragma unroll
      for (int i = 0; i < 4; i++) {
        gload_lds16(aSrc[i] + (size_t)ks * 64, &lsA[lOffA[i]]);
        gload_lds16(bSrc[i] + (size_t)ks * 64, &lsB[lOffA[i]]);
      }
      __syncthreads();
      compute(lsA, lsB);
      __syncthreads();
    }
  }

#pragma unroll
  for (int j = 0; j < 4; j++) {
    const int col = bn * 128 + wnBase + j * 16 + frow;
    const float bb = bias[col];
#pragma unroll
    for (int i = 0; i < 4; i++) {
      const int row0 = bm * 128 + wmBase + i * 16 + kgrp * 4;
      if (MODE == 3 && col >= 2048) {
        const int vcol = col - 2048;
        const int bh = (row0 >> 11) * 16 + (vcol >> 6);
        const int d  = vcol & 63;
        const int kv = row0 & 2047;
        f16x4 pk;
#pragma unroll
        for (int r = 0; r < 4; r++) pk[r] = (f16)(acc[i][j][r] + bb);
        *(f16x4*)(vt + ((size_t)bh * 64 + d) * 2048 + kv) = pk;
      } else {
#pragma unroll
        for (int r = 0; r < 4; r++) {
          float v = acc[i][j][r] + bb;
          if (MODE == 1) v = fmaxf(v, 0.f);
          ((f16*)out)[(size_t)(row0 + r) * N + col] = (f16)v;
        }
      }
    }
  }
}

// ---------------------------------------------------------------------------
// Split-K GEMM (N=1024): partial[kp][4096][1024] f16. Single-buffered LDS
// (32 KB -> 4 blocks/CU residency at grid 1024). KP = 2 or 4.
// COMBINE: A is the attention partials opart[2][32][2048][64]; staging does
// the flash-decoding combine inline (w0*p0 + w1*p1, weights from Lbuf).
template <int KP, bool COMBINE>
__global__ __launch_bounds__(256, 4)
void gemm_splitk(const f16* __restrict__ A, const f16* __restrict__ W,
                 f16* __restrict__ outp, int K, const float* __restrict__ Lb) {
  __shared__ __align__(16) f16 lsA[128 * 64];
  __shared__ __align__(16) f16 lsB[128 * 64];
  const int tid  = threadIdx.x;
  const int lane = tid & 63;
  const int wid  = tid >> 6;
  const int frow = lane & 15;
  const int kgrp = lane >> 4;
  const int wmBase = (wid >> 1) * 64;
  const int wnBase = (wid & 1) * 64;

  // XCD-slab over (bm,kp): xcd owns KP*4 (bm,kp) A-panels x all 8 bn
  const int bid = blockIdx.x;
  const int xcd = bid & 7, slot = bid >> 3;      // slot 0..(KP*32-1)... /8
  const int qq = slot >> 3, bn = slot & 7;
  const int bmkp = xcd * (KP * 4) + qq;          // 0..(32*KP-1)
  const int bm = bmkp / KP, kp = bmkp % KP;
  const int Kh = K / KP;
  const f16* Ab = A + kp * Kh;
  const f16* Wb = W + kp * Kh;

  const f32x4 zero4 = {0.f, 0.f, 0.f, 0.f};
  f32x4 acc[4][4];
#pragma unroll
  for (int i = 0; i < 4; i++)
#pragma unroll
    for (int j = 0; j < 4; j++) acc[i][j] = zero4;

  const f16* aSrc[4]; const f16* bSrc[4]; int lOff[4];
  int rowA[4], chA[4];
#pragma unroll
  for (int i = 0; i < 4; i++) {
    int c_lin = i * 256 + wid * 64 + lane;
    int row = c_lin >> 3;
    int ch  = (c_lin & 7) ^ (row & 7);
    rowA[i] = bm * 128 + row;
    chA[i] = ch;
    aSrc[i] = Ab + (size_t)(bm * 128 + row) * K + ch * 8;
    bSrc[i] = Wb + (size_t)(bn * 128 + row) * K + ch * 8;
    lOff[i] = (i * 256 + wid * 64) * 8;
  }

  const int nk = Kh >> 6;
  for (int ks = 0; ks < nk; ++ks) {
#pragma unroll
    for (int i = 0; i < 4; i++) gload_lds16(bSrc[i] + (size_t)ks * 64, &lsB[lOff[i]]);
    if constexpr (COMBINE) {
      // A = opart[part][bh][2048 q][64 d]; K-step ks covers head h exactly.
      const int h = kp * 8 + ks;                 // Kh=512, nk=8
#pragma unroll
      for (int i = 0; i < 4; i++) {
        const int q = rowA[i] & 2047, bb = rowA[i] >> 11;
        const size_t lidx = (size_t)(bb * 16 + h) * 2048 + q;
        const f16x8 p0 = *(const f16x8*)(A + lidx * 64 + chA[i] * 8);
        const f16x8 p1 = *(const f16x8*)(A + (size_t)65536 * 64 + lidx * 64 + chA[i] * 8);
        const float L0 = Lb[lidx];
        const float L1 = Lb[65536 + lidx];
        const float Lm = fmaxf(L0, L1);
        const float w0 = ex2(L0 - Lm), w1 = ex2(L1 - Lm);
        const float rs = 1.f / (w0 + w1);
        const f16 W0 = (f16)(w0 * rs), W1 = (f16)(w1 * rs);
        f16x8 cv = p0 * W0 + p1 * W1;
        *(f16x8*)(lsA + lOff[i] + lane * 8) = cv;
      }
    } else {
#pragma unroll
      for (int i = 0; i < 4; i++) gload_lds16(aSrc[i] + (size_t)ks * 64, &lsA[lOff[i]]);
    }
    __syncthreads();
#pragma unroll
    for (int kk = 0; kk < 2; kk++) {
      f16x8 af[4], bf[4];
#pragma unroll
      for (int i = 0; i < 4; i++) {
        int row = wmBase + i * 16 + frow;
        af[i] = *(const f16x8*)&lsA[row * 64 + (((kk * 4 + kgrp) ^ (row & 7)) << 3)];
      }
#pragma unroll
      for (int j = 0; j < 4; j++) {
        int row = wnBase + j * 16 + frow;
        bf[j] = *(const f16x8*)&lsB[row * 64 + (((kk * 4 + kgrp) ^ (row & 7)) << 3)];
      }
#pragma unroll
      for (int i = 0; i < 4; i++)
#pragma unroll
        for (int j = 0; j < 4; j++) acc[i][j] = MFMA16(af[i], bf[j], acc[i][j]);
    }
    __syncthreads();
  }

  f16* op = outp + (size_t)kp * 4096 * 1024;
#pragma unroll
  for (int j = 0; j < 4; j++) {
    const int col = bn * 128 + wnBase + j * 16 + frow;
#pragma unroll
    for (int i = 0; i < 4; i++) {
      const int row0 = bm * 128 + wmBase + i * 16 + kgrp * 4;
#pragma unroll
      for (int r = 0; r < 4; r++)
        op[(size_t)(row0 + r) * 1024 + col] = (f16)acc[i][j][r];
    }
  }
}

// ---------------------------------------------------------------------------
// Fused split-K combine (NP parts) + bias + residual + LayerNorm over D=1024.
template <int NP>
__global__ __launch_bounds__(256)
void ln_res2(const f16* __restrict__ p, const f16* __restrict__ res,
             const float* __restrict__ bias, const float* __restrict__ g,
             const float* __restrict__ be, float* __restrict__ of,
             f16* __restrict__ ob) {
  const int row = blockIdx.x, t = threadIdx.x;
  const size_t off = (size_t)row * 1024 + t * 4;
  float v0, v1, v2, v3;
  {
    const f16x4 a = *(const f16x4*)(p + off);
    v0 = (float)a[0]; v1 = (float)a[1]; v2 = (float)a[2]; v3 = (float)a[3];
  }
#pragma unroll
  for (int k = 1; k < NP; k++) {
    const f16x4 a = *(const f16x4*)(p + (size_t)k * 4096 * 1024 + off);
    v0 += (float)a[0]; v1 += (float)a[1]; v2 += (float)a[2]; v3 += (float)a[3];
  }
  const f16x4 rr = *(const f16x4*)(res + off);
  const float4 bb = ((const float4*)bias)[t];
  v0 += bb.x + (float)rr[0];
  v1 += bb.y + (float)rr[1];
  v2 += bb.z + (float)rr[2];
  v3 += bb.w + (float)rr[3];
  float s = v0 + v1 + v2 + v3;
  float q = v0 * v0 + v1 * v1 + v2 * v2 + v3 * v3;
#pragma unroll
  for (int o = 1; o < 64; o <<= 1) {
    s += __shfl_xor(s, o);
    q += __shfl_xor(q, o);
  }
  __shared__ float ss[4], sq[4];
  if ((t & 63) == 0) { ss[t >> 6] = s; sq[t >> 6] = q; }
  __syncthreads();
  s = ss[0] + ss[1] + ss[2] + ss[3];
  q = sq[0] + sq[1] + sq[2] + sq[3];
  const float mean = s * (1.f / 1024.f);
  const float var  = q * (1.f / 1024.f) - mean * mean;
  const float rstd = rsqrtf(var + 1e-5f);
  const float4 gv = ((const float4*)g)[t];
  const float4 bv = ((const float4*)be)[t];
  float4 ov;
  ov.x = (v0 - mean) * rstd * gv.x + bv.x;
  ov.y = (v1 - mean) * rstd * gv.y + bv.y;
  ov.z = (v2 - mean) * rstd * gv.z + bv.z;
  ov.w = (v3 - mean) * rstd * gv.w + bv.w;
  if (of) ((float4*)(of + (size_t)row * 1024))[t] = ov;
  if (ob) {
    f16x4 hv;
    hv[0] = (f16)ov.x; hv[1] = (f16)ov.y; hv[2] = (f16)ov.z; hv[3] = (f16)ov.w;
    *(f16x4*)(ob + off) = hv;
  }
}

// ---------------------------------------------------------------------------
// Flash attention, swapped-QK^T 32x32, KV-split x2.
// l accumulated via MFMA-with-ones; max via v_max3 tree.
__global__ __launch_bounds__(256, 4)
void attn_kernel(const f16* __restrict__ Qp, const f16* __restrict__ Kp,
                 const f16* __restrict__ Vt, f16* __restrict__ opart,
                 float* __restrict__ Lbuf, int ldq) {
  __shared__ __align__(16) f16 lsKb[2 * 64 * 64];
  __shared__ __align__(16) f16 lsVb[2 * 64 * 64];
  const int tid = threadIdx.x, lane = tid & 63, wid = tid >> 6;
  const int qcol = lane & 31;
  const int hi = lane >> 5;
  const int bid = blockIdx.x;
  const int idx = bid >> 3;
  const int bh = ((bid & 7) << 2) | (idx & 3);
  const int rest = idx >> 2;          // 0..31
  const int part = rest & 1;
  const int qt = rest >> 1;           // 0..15
  const int b = bh >> 4, h = bh & 15;
  const size_t rb = (size_t)b * 2048;
  const int hc = h * 64;
  const int kv0 = part * 1024;
  const int qrow = qt * 128 + wid * 32 + qcol;   // 0..2047 (within bh)

  f16x8 qf[4];
  {
    const f16* qp = Qp + (rb + qrow) * ldq + hc;
#pragma unroll
    for (int kc = 0; kc < 4; kc++) qf[kc] = *(const f16x8*)(qp + kc * 16 + hi * 8);
  }
  f16x8 ones;
#pragma unroll
  for (int i = 0; i < 8; i++) ones[i] = (f16)1.0f;

  f32x16 ot0, ot1, lacc;
#pragma unroll
  for (int i = 0; i < 16; i++) { ot0[i] = 0.f; ot1[i] = 0.f; lacc[i] = 0.f; }
  float mrun = -1e30f;

  const f16 *kS0, *kS1, *vS0, *vS1;
  int off0, off1;
  {
    int c0 = wid * 64 + lane;
    int r0 = c0 >> 3, ch0 = (c0 & 7) ^ (r0 & 7);
    int c1 = 256 + wid * 64 + lane;
    int r1 = c1 >> 3, ch1 = (c1 & 7) ^ (r1 & 7);
    kS0 = Kp + (rb + kv0 + r0) * ldq + hc + ch0 * 8;
    kS1 = Kp + (rb + kv0 + r1) * ldq + hc + ch1 * 8;
    const f16* vbase = Vt + (size_t)bh * 64 * 2048 + kv0;
    vS0 = vbase + (size_t)r0 * 2048 + ch0 * 8;
    vS1 = vbase + (size_t)r1 * 2048 + ch1 * 8;
    off0 = (wid * 64) * 8;
    off1 = (256 + wid * 64) * 8;
  }

#define ASTAGE(T, PB)                                                    \
  {                                                                      \
    f16* kd = lsKb + (PB) * 4096;                                        \
    f16* vd = lsVb + (PB) * 4096;                                        \
    const size_t ko = (size_t)(T) * 64 * ldq;                            \
    const size_t vo = (size_t)(T) * 64;                                  \
    gload_lds16(kS0 + ko, kd + off0);                                    \
    gload_lds16(kS1 + ko, kd + off1);                                    \
    gload_lds16(vS0 + vo, vd + off0);                                    \
    gload_lds16(vS1 + vo, vd + off1);                                    \
  }

  ASTAGE(0, 0);
  asm volatile("s_waitcnt vmcnt(0)" ::: "memory");
  __builtin_amdgcn_s_barrier();

  for (int kt = 0; kt < 16; ++kt) {
    const int cur = kt & 1;
    if (kt < 15) ASTAGE(kt + 1, cur ^ 1);   // prefetch overlaps compute below
    const f16* kb = lsKb + cur * 4096;
    const f16* vb = lsVb + cur * 4096;

    // ---- QK^T for both 32-kv subtiles ----
    f32x16 s0, s1;
#pragma unroll
    for (int i = 0; i < 16; i++) { s0[i] = 0.f; s1[i] = 0.f; }
    const int kr0 = qcol, kr1 = 32 + qcol;
    __builtin_amdgcn_s_setprio(1);
#pragma unroll
    for (int kc = 0; kc < 4; kc++) {
      f16x8 a0 = *(const f16x8*)&kb[kr0 * 64 + (((kc * 2 + hi) ^ (kr0 & 7)) << 3)];
      f16x8 a1 = *(const f16x8*)&kb[kr1 * 64 + (((kc * 2 + hi) ^ (kr1 & 7)) << 3)];
      s0 = MFMA32(a0, qf[kc], s0);
      s1 = MFMA32(a1, qf[kc], s1);
    }
    __builtin_amdgcn_s_setprio(0);

    // ---- online softmax (exp2 domain): max via v_max3 tree ----
    float t10[11];
#pragma unroll
    for (int r = 0; r < 10; r++) {
      float e0 = (3 * r + 0 < 16) ? s0[(3 * r + 0) & 15] : s1[(3 * r + 0) & 15];
      float e1 = (3 * r + 1 < 16) ? s0[(3 * r + 1) & 15] : s1[(3 * r + 1) & 15];
      float e2 = (3 * r + 2 < 16) ? s0[(3 * r + 2) & 15] : s1[(3 * r + 2) & 15];
      t10[r] = f3(e0, e1, e2);
    }
    t10[10] = fmaxf(s1[14], s1[15]);
    float p0 = f3(t10[0], t10[1], t10[2]);
    float p1 = f3(t10[3], t10[4], t10[5]);
    float p2 = f3(t10[6], t10[7], t10[8]);
    float p3 = fmaxf(t10[9], t10[10]);
    float pmax = xhalf_max(fmaxf(fmaxf(p0, p1), fmaxf(p2, p3)));
    if (__any(pmax > mrun + 11.54f)) {   // defer-max (T13), 8/ln2
      float mn = fmaxf(mrun, pmax);
      float fac = ex2(mrun - mn);
      mrun = mn;
#pragma unroll
      for (int i = 0; i < 16; i++) {
        ot0[i] *= fac; ot1[i] *= fac; lacc[i] *= fac;
      }
    }
#pragma unroll
    for (int r = 0; r < 16; r++) {
      s0[r] = ex2(s0[r] - mrun);
      s1[r] = ex2(s1[r] - mrun);
    }

    // ---- pack P^T fragments + PV: O^T += V^T @ P^T; l via MFMA-ones ----
#pragma unroll
    for (int st = 0; st < 2; ++st) {
#pragma unroll
      for (int c0 = 0; c0 < 2; c0++) {
        const int c8 = c0 * 8;
        int a0, a1, b0, b1;
        if (st == 0) {
          a0 = pkh(s0[c8 + 0], s0[c8 + 1]); a1 = pkh(s0[c8 + 2], s0[c8 + 3]);
          b0 = pkh(s0[c8 + 4], s0[c8 + 5]); b1 = pkh(s0[c8 + 6], s0[c8 + 7]);
        } else {
          a0 = pkh(s1[c8 + 0], s1[c8 + 1]); a1 = pkh(s1[c8 + 2], s1[c8 + 3]);
          b0 = pkh(s1[c8 + 4], s1[c8 + 5]); b1 = pkh(s1[c8 + 6], s1[c8 + 7]);
        }
        uint2v r0 = pswap(a0, b0);
        uint2v r1 = pswap(a1, b1);
        int4 wv;
        wv.x = (int)r0.x; wv.y = (int)r1.x; wv.z = (int)r0.y; wv.w = (int)r1.y;
        f16x8 pfrag = __builtin_bit_cast(f16x8, wv);
        const int ch = st * 4 + c0 * 2 + hi;   // 16B chunk of kv window
        const int vr0 = qcol, vr1 = 32 + qcol;
        f16x8 av0 = *(const f16x8*)&vb[vr0 * 64 + ((ch ^ (vr0 & 7)) << 3)];
        f16x8 av1 = *(const f16x8*)&vb[vr1 * 64 + ((ch ^ (vr1 & 7)) << 3)];
        __builtin_amdgcn_s_setprio(1);
        ot0 = MFMA32(av0, pfrag, ot0);
        ot1 = MFMA32(av1, pfrag, ot1);
        lacc = MFMA32(ones, pfrag, lacc);   // row-sums of P^T -> l (free sum)
        __builtin_amdgcn_s_setprio(0);
      }
    }
    asm volatile("s_waitcnt vmcnt(0)" ::: "memory");  // prefetch landed
    __builtin_amdgcn_s_barrier();
  }
#undef ASTAGE

  // ---- partial epilogue: Ohat = O/l (f16), Li = m + log2(l) ----
  const float lfin = lacc[0];            // all 16 regs identical = sum_kv p
  const float rinv = 1.f / lfin;
  const size_t pbase = ((size_t)part * 32 + bh) * 2048 + qrow;
  f16* pp = opart + pbase * 64;
#pragma unroll
  for (int rr = 0; rr < 16; rr += 2) {
    const int d = (rr & 3) + 8 * (rr >> 2) + 4 * hi;
    *(int*)(pp + d)      = pkh(ot0[rr] * rinv, ot0[rr + 1] * rinv);
    *(int*)(pp + 32 + d) = pkh(ot1[rr] * rinv, ot1[rr + 1] * rinv);
  }
  if (hi == 0) Lbuf[pbase] = mrun + __builtin_amdgcn_logf(lfin);  // log2
}

// ---------------------------------------------------------------------------
extern "C" void kernel_launch(void* const* d_in, const int* in_sizes, int n_in,
                              void* d_out, int out_size, void* d_ws, size_t ws_size,
                              hipStream_t stream) {
  const float* x   = (const float*)d_in[0];
  const float* pW1 = (const float*)d_in[1];
  const float* pb1 = (const float*)d_in[2];
  const float* pW2 = (const float*)d_in[3];
  const float* pb2 = (const float*)d_in[4];
  const float* gp  = (const float*)d_in[5];
  const float* bp  = (const float*)d_in[6];
  const float* Wq  = (const float*)d_in[7];
  const float* bq  = (const float*)d_in[8];
  const float* Wk  = (const float*)d_in[9];
  const float* bk  = (const float*)d_in[10];
  const float* Wv  = (const float*)d_in[11];
  const float* bv  = (const float*)d_in[12];
  const float* Wo  = (const float*)d_in[13];
  const float* bo  = (const float*)d_in[14];
  const float* g1  = (const float*)d_in[15];
  const float* b1  = (const float*)d_in[16];
  const float* Wf1 = (const float*)d_in[17];
  const float* bf1 = (const float*)d_in[18];
  const float* Wf2 = (const float*)d_in[19];
  const float* bf2 = (const float*)d_in[20];
  const float* g2  = (const float*)d_in[21];
  const float* b2  = (const float*)d_in[22];

  char* ws = (char*)d_ws;
  const size_t MB = 1024 * 1024;
  if (ws_size < 121 * MB) return;

  f16*   wtP1 = (f16*)(ws);              // [2048][1024]  4 MB
  f16*   wtP2 = (f16*)(ws + 4 * MB);     // [1024][2048]  4 MB
  f16*   wtQ  = (f16*)(ws + 8 * MB);     // [3072][1024]  6 MB fused qkv weights
  f16*   wtO  = (f16*)(ws + 14 * MB);    // [1024][1024]  2 MB
  f16*   wtF1 = (f16*)(ws + 16 * MB);    // [4096][1024]  8 MB
  f16*   wtF2 = (f16*)(ws + 24 * MB);    // [1024][4096]  8 MB
  f16*   big  = (f16*)(ws + 32 * MB);    // 32 MB: h1 / qk(24)+Vt(8) / f1
  f16*   xb   = (f16*)(ws + 64 * MB);    // 8 MB f16 x
  f16*   sb   = (f16*)(ws + 72 * MB);    // 8 MB s = LN1 out
  f16*   ybuf = (f16*)(ws + 80 * MB);    // 8 MB y = LN2 out
  f16*   part = (f16*)(ws + 88 * MB);    // up to 32 MB split-K partials (4x8MB)
  f16*   opart= (f16*)(ws + 88 * MB);    // 16 MB attn partials (disjoint lifetime w/ part4)
  f16*   partO= (f16*)(ws + 104 * MB);   // 16 MB O-proj split-K partials (2x8MB)
  float* Lbuf = (float*)(ws + 120 * MB); // 0.5 MB [2][32][2048]
  float* bqkv = (float*)(ws + 120 * MB + 512 * 1024); // 12 KB
  f16*   wtK  = wtQ + (size_t)1024 * 1024;
  f16*   wtV  = wtQ + (size_t)2048 * 1024;
  f16*   Vt   = big + (size_t)4096 * 3072; // V^T [32 bh][64 d][2048 kv]

  dim3 blk(256);
  // one mega prep launch: cast + 9 wtrans + qkv bias
  prep_kernel<<<20492, blk, 0, stream>>>(x, xb, pW1, wtP1, pW2, wtP2,
                                         Wq, wtQ, Wk, wtK, Wv, wtV, Wo, wtO,
                                         Wf1, wtF1, Wf2, wtF2, bq, bk, bv, bqkv);

  // h1 = relu(x @ pW1 + pb1)            [4096][2048] f16 in big
  gemm_kernel<1, true><<<512, blk, 0, stream>>>(xb, wtP1, pb1, big, nullptr, 2048, 1024, 16);
  // part[0..4) = h1 @ pW2 (split-K=4), then LN1: s = LN(x + sum(part) + pb2)
  gemm_splitk<4, false><<<1024, blk, 0, stream>>>(big, wtP2, part, 2048, nullptr);
  ln_res2<4><<<4096, blk, 0, stream>>>(part, xb, pb2, gp, bp, nullptr, sb);
  // qkv = s @ [Wq|Wk|Wv] + bias; Q,K normal (ld 3072), V transposed into Vt
  gemm_kernel<3, false><<<768, blk, 0, stream>>>(sb, wtQ, bqkv, big, Vt, 3072, 1024, 24);
  // attention partials (KV-split x2) -> opart, Lbuf
  attn_kernel<<<1024, blk, 0, stream>>>(big, big + 1024, Vt, opart, Lbuf, 3072);
  // partO = combine(opart) @ Wo (split-K=2, combine fused into A-staging)
  gemm_splitk<2, true><<<512, blk, 0, stream>>>(opart, wtO, partO, 1024, Lbuf);
  ln_res2<2><<<4096, blk, 0, stream>>>(partO, sb, bo, g1, b1, nullptr, ybuf);
  // f1 = relu(y @ Wf1 + bf1)            [4096][4096] f16 in big
  gemm_kernel<1, false><<<1024, blk, 0, stream>>>(ybuf, wtF1, bf1, big, nullptr, 4096, 1024, 32);
  // part[0..4) = f1 @ Wf2 (split-K=4), then LN3 -> f32 d_out
  gemm_splitk<4, false><<<1024, blk, 0, stream>>>(big, wtF2, part, 4096, nullptr);
  ln_res2<4><<<4096, blk, 0, stream>>>(part, ybuf, bf2, g2, b2, (float*)d_out, nullptr);
}

// Round 12
// 271.165 us; speedup vs baseline: 1.1272x; 1.1272x over previous
//
#include <hip/hip_runtime.h>
#include <cstdint>
#include <cstddef>

typedef _Float16 f16;
typedef _Float16 f16x8 __attribute__((ext_vector_type(8)));
typedef _Float16 f16x4 __attribute__((ext_vector_type(4)));
typedef float    f32x4 __attribute__((ext_vector_type(4)));
typedef float    f32x16 __attribute__((ext_vector_type(16)));
typedef unsigned int uint2v __attribute__((ext_vector_type(2)));

#define MFMA16(a,b,c) __builtin_amdgcn_mfma_f32_16x16x32_f16(a, b, c, 0, 0, 0)
#define MFMA32(a,b,c) __builtin_amdgcn_mfma_f32_32x32x16_f16(a, b, c, 0, 0, 0)

static __device__ __forceinline__ void gload_lds16(const void* g, void* l) {
  __builtin_amdgcn_global_load_lds(
      (const __attribute__((address_space(1))) unsigned int*)g,
      (__attribute__((address_space(3))) unsigned int*)l, 16, 0, 0);
}

static __device__ __forceinline__ int pkh(float a, float b) {
  auto t = __builtin_amdgcn_cvt_pkrtz(a, b);   // __fp16 x2
  return __builtin_bit_cast(int, t);
}

static __device__ __forceinline__ float ex2(float x) {
  return __builtin_amdgcn_exp2f(x);
}

// v_permlane32_swap: returns {a', b'} with a' = [a_lo | b_lo], b' = [a_hi | b_hi]
static __device__ __forceinline__ uint2v pswap(int a, int b) {
  return __builtin_amdgcn_permlane32_swap((unsigned)a, (unsigned)b, false, false);
}
static __device__ __forceinline__ float xhalf_max(float x) {
  uint2v r = pswap(__builtin_bit_cast(int, x), __builtin_bit_cast(int, x));
  return fmaxf(__builtin_bit_cast(float, r.x), __builtin_bit_cast(float, r.y));
}
static __device__ __forceinline__ float f3(float a, float b, float c) {
  return fmaxf(fmaxf(a, b), c);    // fuses to v_max3_f32
}

// ---------------------------------------------------------------------------
// Mega prep kernel: f32->f16 cast of x, all 9 weight transposes, qkv bias.
static __device__ __forceinline__ void wtrans_blk(float (*tile)[33],
                                                  const float* __restrict__ W,
                                                  f16* __restrict__ Wt,
                                                  int K, int N, int gx,
                                                  float scale, int lb) {
  const int n0 = (lb % gx) * 32, k0 = (lb / gx) * 32;
  const int c = threadIdx.x & 31, r = threadIdx.x >> 5;  // r: 0..7
#pragma unroll
  for (int i = 0; i < 4; i++) {
    int row = r + i * 8;
    tile[row][c] = W[(size_t)(k0 + row) * N + n0 + c];
  }
  __syncthreads();
#pragma unroll
  for (int i = 0; i < 4; i++) {
    int row = r + i * 8;
    Wt[(size_t)(n0 + row) * K + k0 + c] = (f16)(tile[c][row] * scale);
  }
}

__global__ __launch_bounds__(256)
void prep_kernel(const float* __restrict__ x, f16* __restrict__ xb,
                 const float* __restrict__ pW1, f16* __restrict__ wtP1,
                 const float* __restrict__ pW2, f16* __restrict__ wtP2,
                 const float* __restrict__ Wq,  f16* __restrict__ wtQ,
                 const float* __restrict__ Wk,  f16* __restrict__ wtK,
                 const float* __restrict__ Wv,  f16* __restrict__ wtV,
                 const float* __restrict__ Wo,  f16* __restrict__ wtO,
                 const float* __restrict__ Wf1, f16* __restrict__ wtF1,
                 const float* __restrict__ Wf2, f16* __restrict__ wtF2,
                 const float* __restrict__ bq, const float* __restrict__ bk,
                 const float* __restrict__ bv, float* __restrict__ bqkv) {
  __shared__ float tile[32][33];
  int b = blockIdx.x;
  if (b < 4096) {                       // cast x -> f16
    int i = b * 256 + threadIdx.x;
    float4 v = ((const float4*)x)[i];
    f16x4 h;
    h[0] = (f16)v.x; h[1] = (f16)v.y; h[2] = (f16)v.z; h[3] = (f16)v.w;
    *(f16x4*)(xb + (size_t)i * 4) = h;
    return;
  }
  b -= 4096;
  if (b < 2048) { wtrans_blk(tile, pW1, wtP1, 1024, 2048, 64, 1.f, b); return; }
  b -= 2048;
  if (b < 2048) { wtrans_blk(tile, pW2, wtP2, 2048, 1024, 32, 1.f, b); return; }
  b -= 2048;
  if (b < 1024) { wtrans_blk(tile, Wq, wtQ, 1024, 1024, 32, 0.18033688f, b); return; }
  b -= 1024;
  if (b < 1024) { wtrans_blk(tile, Wk, wtK, 1024, 1024, 32, 1.f, b); return; }
  b -= 1024;
  if (b < 1024) { wtrans_blk(tile, Wv, wtV, 1024, 1024, 32, 1.f, b); return; }
  b -= 1024;
  if (b < 1024) { wtrans_blk(tile, Wo, wtO, 1024, 1024, 32, 1.f, b); return; }
  b -= 1024;
  if (b < 4096) { wtrans_blk(tile, Wf1, wtF1, 1024, 4096, 128, 1.f, b); return; }
  b -= 4096;
  if (b < 4096) { wtrans_blk(tile, Wf2, wtF2, 4096, 1024, 32, 1.f, b); return; }
  b -= 4096;
  {                                     // qkv bias (12 blocks)
    int i = b * 256 + threadIdx.x;
    if (i < 1024)       bqkv[i] = bq[i] * 0.18033688f;
    else if (i < 2048)  bqkv[i] = bk[i - 1024];
    else if (i < 3072)  bqkv[i] = bv[i - 2048];
  }
}

// ---------------------------------------------------------------------------
// GEMM: out = epilogue(A[M][K]_f16 @ W^T[N][K]_f16 + bias)
// MODE 1: relu + f16 store
// MODE 3: f16 store, except cols>=2048 stored transposed to vt[bh][64][2048]
// PF: double-buffered LDS + counted-vmcnt prefetch (for grid-512 launches
// with only 2 blocks/CU of TLP). XCD-slab mapping (gy=32).
template <int MODE, bool PF>
__global__ __launch_bounds__(256, 2)
void gemm_kernel(const f16* __restrict__ A, const f16* __restrict__ W,
                 const float* __restrict__ bias, void* __restrict__ out,
                 f16* __restrict__ vt, int N, int K, int gx) {
  constexpr int BUFS = PF ? 2 : 1;
  __shared__ __align__(16) f16 lsA[BUFS * 128 * 64];
  __shared__ __align__(16) f16 lsB[BUFS * 128 * 64];
  const int tid  = threadIdx.x;
  const int lane = tid & 63;
  const int wid  = tid >> 6;
  const int frow = lane & 15;
  const int kgrp = lane >> 4;
  const int wmBase = (wid >> 1) * 64;
  const int wnBase = (wid & 1) * 64;

  const int bid = blockIdx.x;
  const int xcd = bid & 7, slot = bid >> 3;
  const int bm = (xcd << 2) + slot / gx;
  const int bn = slot % gx;

  const f32x4 zero4 = {0.f, 0.f, 0.f, 0.f};
  f32x4 acc[4][4];
#pragma unroll
  for (int i = 0; i < 4; i++)
#pragma unroll
    for (int j = 0; j < 4; j++) acc[i][j] = zero4;

  const f16* aSrc[4]; int lOffA[4];
  const f16* bSrc[4];
#pragma unroll
  for (int i = 0; i < 4; i++) {
    int c_lin = i * 256 + wid * 64 + lane;       // chunk id (16B units)
    int row = c_lin >> 3;
    int ch  = (c_lin & 7) ^ (row & 7);           // inverse-swizzled source chunk
    aSrc[i] = A + (size_t)(bm * 128 + row) * K + ch * 8;
    bSrc[i] = W + (size_t)(bn * 128 + row) * K + ch * 8;
    lOffA[i] = (i * 256 + wid * 64) * 8;
  }

  auto compute = [&](const f16* la, const f16* lb) {
#pragma unroll
    for (int kk = 0; kk < 2; kk++) {
      f16x8 af[4], bf[4];
#pragma unroll
      for (int i = 0; i < 4; i++) {
        int row = wmBase + i * 16 + frow;
        af[i] = *(const f16x8*)&la[row * 64 + (((kk * 4 + kgrp) ^ (row & 7)) << 3)];
      }
#pragma unroll
      for (int j = 0; j < 4; j++) {
        int row = wnBase + j * 16 + frow;
        bf[j] = *(const f16x8*)&lb[row * 64 + (((kk * 4 + kgrp) ^ (row & 7)) << 3)];
      }
#pragma unroll
      for (int i = 0; i < 4; i++)
#pragma unroll
        for (int j = 0; j < 4; j++) acc[i][j] = MFMA16(af[i], bf[j], acc[i][j]);
    }
  };

  const int nk = K >> 6;
  if constexpr (PF) {
#define GST(T, PB)                                                        \
    {                                                                     \
      f16* la = lsA + (PB) * 8192;                                        \
      f16* lb = lsB + (PB) * 8192;                                        \
      _Pragma("unroll") for (int i = 0; i < 4; i++) {                     \
        gload_lds16(aSrc[i] + (size_t)(T) * 64, la + lOffA[i]);           \
        gload_lds16(bSrc[i] + (size_t)(T) * 64, lb + lOffA[i]);           \
      }                                                                   \
    }
    GST(0, 0);
    for (int ks = 0; ks < nk; ++ks) {
      const int nt = (ks + 1 < nk) ? ks + 1 : nk - 1;   // dup-stage last tile
      GST(nt, (ks + 1) & 1);
      asm volatile("s_waitcnt vmcnt(8)" ::: "memory");  // tile ks landed
      __builtin_amdgcn_s_barrier();
      compute(lsA + (ks & 1) * 8192, lsB + (ks & 1) * 8192);
      __builtin_amdgcn_s_barrier();                     // buf free for ks+2
    }
    asm volatile("s_waitcnt vmcnt(0)" ::: "memory");    // drain dup-stage
#undef GST
  } else {
    for (int ks = 0; ks < nk; ++ks) {
#pragma unroll
      for (int i = 0; i < 4; i++) {
        gload_lds16(aSrc[i] + (size_t)ks * 64, &lsA[lOffA[i]]);
        gload_lds16(bSrc[i] + (size_t)ks * 64, &lsB[lOffA[i]]);
      }
      __syncthreads();
      compute(lsA, lsB);
      __syncthreads();
    }
  }

#pragma unroll
  for (int j = 0; j < 4; j++) {
    const int col = bn * 128 + wnBase + j * 16 + frow;
    const float bb = bias[col];
#pragma unroll
    for (int i = 0; i < 4; i++) {
      const int row0 = bm * 128 + wmBase + i * 16 + kgrp * 4;
      if (MODE == 3 && col >= 2048) {
        const int vcol = col - 2048;
        const int bh = (row0 >> 11) * 16 + (vcol >> 6);
        const int d  = vcol & 63;
        const int kv = row0 & 2047;
        f16x4 pk;
#pragma unroll
        for (int r = 0; r < 4; r++) pk[r] = (f16)(acc[i][j][r] + bb);
        *(f16x4*)(vt + ((size_t)bh * 64 + d) * 2048 + kv) = pk;
      } else {
#pragma unroll
        for (int r = 0; r < 4; r++) {
          float v = acc[i][j][r] + bb;
          if (MODE == 1) v = fmaxf(v, 0.f);
          ((f16*)out)[(size_t)(row0 + r) * N + col] = (f16)v;
        }
      }
    }
  }
}

// ---------------------------------------------------------------------------
// Split-K=2 GEMM (N=1024, grid 512): partial[kp][4096][1024] f16.
// Prefetch-pipelined (2 blocks/CU only — needs within-block overlap).
__global__ __launch_bounds__(256, 2)
void gemm_splitk(const f16* __restrict__ A, const f16* __restrict__ W,
                 f16* __restrict__ outp, int K) {
  __shared__ __align__(16) f16 lsA[2 * 128 * 64];
  __shared__ __align__(16) f16 lsB[2 * 128 * 64];
  const int tid  = threadIdx.x;
  const int lane = tid & 63;
  const int wid  = tid >> 6;
  const int frow = lane & 15;
  const int kgrp = lane >> 4;
  const int wmBase = (wid >> 1) * 64;
  const int wnBase = (wid & 1) * 64;

  // XCD-slab over (bm,kp): xcd owns 8 (bm,kp) A-panels x all 8 bn
  const int bid = blockIdx.x;
  const int xcd = bid & 7, slot = bid >> 3;      // slot 0..63
  const int q = slot >> 3, bn = slot & 7;
  const int bmkp = xcd * 8 + q;                  // 0..63
  const int bm = bmkp >> 1, kp = bmkp & 1;
  const int Kh = K >> 1;
  const f16* Ab = A + kp * Kh;
  const f16* Wb = W + kp * Kh;

  const f32x4 zero4 = {0.f, 0.f, 0.f, 0.f};
  f32x4 acc[4][4];
#pragma unroll
  for (int i = 0; i < 4; i++)
#pragma unroll
    for (int j = 0; j < 4; j++) acc[i][j] = zero4;

  const f16* aSrc[4]; const f16* bSrc[4]; int lOff[4];
#pragma unroll
  for (int i = 0; i < 4; i++) {
    int c_lin = i * 256 + wid * 64 + lane;
    int row = c_lin >> 3;
    int ch  = (c_lin & 7) ^ (row & 7);
    aSrc[i] = Ab + (size_t)(bm * 128 + row) * K + ch * 8;
    bSrc[i] = Wb + (size_t)(bn * 128 + row) * K + ch * 8;
    lOff[i] = (i * 256 + wid * 64) * 8;
  }

  auto compute = [&](const f16* la, const f16* lb) {
#pragma unroll
    for (int kk = 0; kk < 2; kk++) {
      f16x8 af[4], bf[4];
#pragma unroll
      for (int i = 0; i < 4; i++) {
        int row = wmBase + i * 16 + frow;
        af[i] = *(const f16x8*)&la[row * 64 + (((kk * 4 + kgrp) ^ (row & 7)) << 3)];
      }
#pragma unroll
      for (int j = 0; j < 4; j++) {
        int row = wnBase + j * 16 + frow;
        bf[j] = *(const f16x8*)&lb[row * 64 + (((kk * 4 + kgrp) ^ (row & 7)) << 3)];
      }
#pragma unroll
      for (int i = 0; i < 4; i++)
#pragma unroll
        for (int j = 0; j < 4; j++) acc[i][j] = MFMA16(af[i], bf[j], acc[i][j]);
    }
  };

#define GST(T, PB)                                                        \
  {                                                                       \
    f16* la = lsA + (PB) * 8192;                                          \
    f16* lb = lsB + (PB) * 8192;                                          \
    _Pragma("unroll") for (int i = 0; i < 4; i++) {                       \
      gload_lds16(aSrc[i] + (size_t)(T) * 64, la + lOff[i]);              \
      gload_lds16(bSrc[i] + (size_t)(T) * 64, lb + lOff[i]);              \
    }                                                                     \
  }
  const int nk = Kh >> 6;
  GST(0, 0);
  for (int ks = 0; ks < nk; ++ks) {
    const int nt = (ks + 1 < nk) ? ks + 1 : nk - 1;
    GST(nt, (ks + 1) & 1);
    asm volatile("s_waitcnt vmcnt(8)" ::: "memory");
    __builtin_amdgcn_s_barrier();
    compute(lsA + (ks & 1) * 8192, lsB + (ks & 1) * 8192);
    __builtin_amdgcn_s_barrier();
  }
  asm volatile("s_waitcnt vmcnt(0)" ::: "memory");
#undef GST

  f16* op = outp + (size_t)kp * 4096 * 1024;
#pragma unroll
  for (int j = 0; j < 4; j++) {
    const int col = bn * 128 + wnBase + j * 16 + frow;
#pragma unroll
    for (int i = 0; i < 4; i++) {
      const int row0 = bm * 128 + wmBase + i * 16 + kgrp * 4;
#pragma unroll
      for (int r = 0; r < 4; r++)
        op[(size_t)(row0 + r) * 1024 + col] = (f16)acc[i][j][r];
    }
  }
}

// ---------------------------------------------------------------------------
// Fused split-K combine + bias + residual + LayerNorm over D=1024.
__global__ __launch_bounds__(256)
void ln_res2(const f16* __restrict__ p, const f16* __restrict__ res,
             const float* __restrict__ bias, const float* __restrict__ g,
             const float* __restrict__ be, float* __restrict__ of,
             f16* __restrict__ ob) {
  const int row = blockIdx.x, t = threadIdx.x;
  const size_t off = (size_t)row * 1024 + t * 4;
  const f16x4 a = *(const f16x4*)(p + off);
  const f16x4 b = *(const f16x4*)(p + (size_t)4096 * 1024 + off);
  const f16x4 rr = *(const f16x4*)(res + off);
  const float4 bb = ((const float4*)bias)[t];
  float v0 = (float)a[0] + (float)b[0] + bb.x + (float)rr[0];
  float v1 = (float)a[1] + (float)b[1] + bb.y + (float)rr[1];
  float v2 = (float)a[2] + (float)b[2] + bb.z + (float)rr[2];
  float v3 = (float)a[3] + (float)b[3] + bb.w + (float)rr[3];
  float s = v0 + v1 + v2 + v3;
  float q = v0 * v0 + v1 * v1 + v2 * v2 + v3 * v3;
#pragma unroll
  for (int o = 1; o < 64; o <<= 1) {
    s += __shfl_xor(s, o);
    q += __shfl_xor(q, o);
  }
  __shared__ float ss[4], sq[4];
  if ((t & 63) == 0) { ss[t >> 6] = s; sq[t >> 6] = q; }
  __syncthreads();
  s = ss[0] + ss[1] + ss[2] + ss[3];
  q = sq[0] + sq[1] + sq[2] + sq[3];
  const float mean = s * (1.f / 1024.f);
  const float var  = q * (1.f / 1024.f) - mean * mean;
  const float rstd = rsqrtf(var + 1e-5f);
  const float4 gv = ((const float4*)g)[t];
  const float4 bv = ((const float4*)be)[t];
  float4 ov;
  ov.x = (v0 - mean) * rstd * gv.x + bv.x;
  ov.y = (v1 - mean) * rstd * gv.y + bv.y;
  ov.z = (v2 - mean) * rstd * gv.z + bv.z;
  ov.w = (v3 - mean) * rstd * gv.w + bv.w;
  if (of) ((float4*)(of + (size_t)row * 1024))[t] = ov;
  if (ob) {
    f16x4 hv;
    hv[0] = (f16)ov.x; hv[1] = (f16)ov.y; hv[2] = (f16)ov.z; hv[3] = (f16)ov.w;
    *(f16x4*)(ob + off) = hv;
  }
}

// ---------------------------------------------------------------------------
// Flash attention, swapped-QK^T 32x32, KV-split x2.
// l accumulated via MFMA-with-ones; max via v_max3 tree.
__global__ __launch_bounds__(256, 4)
void attn_kernel(const f16* __restrict__ Qp, const f16* __restrict__ Kp,
                 const f16* __restrict__ Vt, f16* __restrict__ opart,
                 float* __restrict__ Lbuf, int ldq) {
  __shared__ __align__(16) f16 lsKb[2 * 64 * 64];
  __shared__ __align__(16) f16 lsVb[2 * 64 * 64];
  const int tid = threadIdx.x, lane = tid & 63, wid = tid >> 6;
  const int qcol = lane & 31;
  const int hi = lane >> 5;
  const int bid = blockIdx.x;
  const int idx = bid >> 3;
  const int bh = ((bid & 7) << 2) | (idx & 3);
  const int rest = idx >> 2;          // 0..31
  const int part = rest & 1;
  const int qt = rest >> 1;           // 0..15
  const int b = bh >> 4, h = bh & 15;
  const size_t rb = (size_t)b * 2048;
  const int hc = h * 64;
  const int kv0 = part * 1024;
  const int qrow = qt * 128 + wid * 32 + qcol;   // 0..2047 (within bh)

  f16x8 qf[4];
  {
    const f16* qp = Qp + (rb + qrow) * ldq + hc;
#pragma unroll
    for (int kc = 0; kc < 4; kc++) qf[kc] = *(const f16x8*)(qp + kc * 16 + hi * 8);
  }
  f16x8 ones;
#pragma unroll
  for (int i = 0; i < 8; i++) ones[i] = (f16)1.0f;

  f32x16 ot0, ot1, lacc;
#pragma unroll
  for (int i = 0; i < 16; i++) { ot0[i] = 0.f; ot1[i] = 0.f; lacc[i] = 0.f; }
  float mrun = -1e30f;

  const f16 *kS0, *kS1, *vS0, *vS1;
  int off0, off1;
  {
    int c0 = wid * 64 + lane;
    int r0 = c0 >> 3, ch0 = (c0 & 7) ^ (r0 & 7);
    int c1 = 256 + wid * 64 + lane;
    int r1 = c1 >> 3, ch1 = (c1 & 7) ^ (r1 & 7);
    kS0 = Kp + (rb + kv0 + r0) * ldq + hc + ch0 * 8;
    kS1 = Kp + (rb + kv0 + r1) * ldq + hc + ch1 * 8;
    const f16* vbase = Vt + (size_t)bh * 64 * 2048 + kv0;
    vS0 = vbase + (size_t)r0 * 2048 + ch0 * 8;
    vS1 = vbase + (size_t)r1 * 2048 + ch1 * 8;
    off0 = (wid * 64) * 8;
    off1 = (256 + wid * 64) * 8;
  }

#define ASTAGE(T, PB)                                                    \
  {                                                                      \
    f16* kd = lsKb + (PB) * 4096;                                        \
    f16* vd = lsVb + (PB) * 4096;                                        \
    const size_t ko = (size_t)(T) * 64 * ldq;                            \
    const size_t vo = (size_t)(T) * 64;                                  \
    gload_lds16(kS0 + ko, kd + off0);                                    \
    gload_lds16(kS1 + ko, kd + off1);                                    \
    gload_lds16(vS0 + vo, vd + off0);                                    \
    gload_lds16(vS1 + vo, vd + off1);                                    \
  }

  ASTAGE(0, 0);
  asm volatile("s_waitcnt vmcnt(0)" ::: "memory");
  __builtin_amdgcn_s_barrier();

  for (int kt = 0; kt < 16; ++kt) {
    const int cur = kt & 1;
    if (kt < 15) ASTAGE(kt + 1, cur ^ 1);   // prefetch overlaps compute below
    const f16* kb = lsKb + cur * 4096;
    const f16* vb = lsVb + cur * 4096;

    // ---- QK^T for both 32-kv subtiles ----
    f32x16 s0, s1;
#pragma unroll
    for (int i = 0; i < 16; i++) { s0[i] = 0.f; s1[i] = 0.f; }
    const int kr0 = qcol, kr1 = 32 + qcol;
    __builtin_amdgcn_s_setprio(1);
#pragma unroll
    for (int kc = 0; kc < 4; kc++) {
      f16x8 a0 = *(const f16x8*)&kb[kr0 * 64 + (((kc * 2 + hi) ^ (kr0 & 7)) << 3)];
      f16x8 a1 = *(const f16x8*)&kb[kr1 * 64 + (((kc * 2 + hi) ^ (kr1 & 7)) << 3)];
      s0 = MFMA32(a0, qf[kc], s0);
      s1 = MFMA32(a1, qf[kc], s1);
    }
    __builtin_amdgcn_s_setprio(0);

    // ---- online softmax (exp2 domain): max via v_max3 tree ----
    float t10[11];
#pragma unroll
    for (int r = 0; r < 10; r++) {
      float e0 = (3 * r + 0 < 16) ? s0[(3 * r + 0) & 15] : s1[(3 * r + 0) & 15];
      float e1 = (3 * r + 1 < 16) ? s0[(3 * r + 1) & 15] : s1[(3 * r + 1) & 15];
      float e2 = (3 * r + 2 < 16) ? s0[(3 * r + 2) & 15] : s1[(3 * r + 2) & 15];
      t10[r] = f3(e0, e1, e2);
    }
    t10[10] = fmaxf(s1[14], s1[15]);
    float p0 = f3(t10[0], t10[1], t10[2]);
    float p1 = f3(t10[3], t10[4], t10[5]);
    float p2 = f3(t10[6], t10[7], t10[8]);
    float p3 = fmaxf(t10[9], t10[10]);
    float pmax = xhalf_max(fmaxf(fmaxf(p0, p1), fmaxf(p2, p3)));
    if (__any(pmax > mrun + 11.54f)) {   // defer-max (T13), 8/ln2
      float mn = fmaxf(mrun, pmax);
      float fac = ex2(mrun - mn);
      mrun = mn;
#pragma unroll
      for (int i = 0; i < 16; i++) {
        ot0[i] *= fac; ot1[i] *= fac; lacc[i] *= fac;
      }
    }
#pragma unroll
    for (int r = 0; r < 16; r++) {
      s0[r] = ex2(s0[r] - mrun);
      s1[r] = ex2(s1[r] - mrun);
    }

    // ---- pack P^T fragments + PV: O^T += V^T @ P^T; l via MFMA-ones ----
#pragma unroll
    for (int st = 0; st < 2; ++st) {
#pragma unroll
      for (int c0 = 0; c0 < 2; c0++) {
        const int c8 = c0 * 8;
        int a0, a1, b0, b1;
        if (st == 0) {
          a0 = pkh(s0[c8 + 0], s0[c8 + 1]); a1 = pkh(s0[c8 + 2], s0[c8 + 3]);
          b0 = pkh(s0[c8 + 4], s0[c8 + 5]); b1 = pkh(s0[c8 + 6], s0[c8 + 7]);
        } else {
          a0 = pkh(s1[c8 + 0], s1[c8 + 1]); a1 = pkh(s1[c8 + 2], s1[c8 + 3]);
          b0 = pkh(s1[c8 + 4], s1[c8 + 5]); b1 = pkh(s1[c8 + 6], s1[c8 + 7]);
        }
        uint2v r0 = pswap(a0, b0);
        uint2v r1 = pswap(a1, b1);
        int4 wv;
        wv.x = (int)r0.x; wv.y = (int)r1.x; wv.z = (int)r0.y; wv.w = (int)r1.y;
        f16x8 pfrag = __builtin_bit_cast(f16x8, wv);
        const int ch = st * 4 + c0 * 2 + hi;   // 16B chunk of kv window
        const int vr0 = qcol, vr1 = 32 + qcol;
        f16x8 av0 = *(const f16x8*)&vb[vr0 * 64 + ((ch ^ (vr0 & 7)) << 3)];
        f16x8 av1 = *(const f16x8*)&vb[vr1 * 64 + ((ch ^ (vr1 & 7)) << 3)];
        __builtin_amdgcn_s_setprio(1);
        ot0 = MFMA32(av0, pfrag, ot0);
        ot1 = MFMA32(av1, pfrag, ot1);
        lacc = MFMA32(ones, pfrag, lacc);   // row-sums of P^T -> l (free sum)
        __builtin_amdgcn_s_setprio(0);
      }
    }
    asm volatile("s_waitcnt vmcnt(0)" ::: "memory");  // prefetch landed
    __builtin_amdgcn_s_barrier();
  }
#undef ASTAGE

  // ---- partial epilogue: Ohat = O/l (f16), Li = m + log2(l) ----
  const float lfin = lacc[0];            // all 16 regs identical = sum_kv p
  const float rinv = 1.f / lfin;
  const size_t pbase = ((size_t)part * 32 + bh) * 2048 + qrow;
  f16* pp = opart + pbase * 64;
#pragma unroll
  for (int rr = 0; rr < 16; rr += 2) {
    const int d = (rr & 3) + 8 * (rr >> 2) + 4 * hi;
    *(int*)(pp + d)      = pkh(ot0[rr] * rinv, ot0[rr + 1] * rinv);
    *(int*)(pp + 32 + d) = pkh(ot1[rr] * rinv, ot1[rr + 1] * rinv);
  }
  if (hi == 0) Lbuf[pbase] = mrun + __builtin_amdgcn_logf(lfin);  // log2
}

// ---------------------------------------------------------------------------
// Combine the two KV-split partials -> ctx f16 [B*S][1024]
__global__ __launch_bounds__(256)
void combine_kernel(const f16* __restrict__ opart, const float* __restrict__ Lbuf,
                    f16* __restrict__ ctx) {
  const int bid = blockIdx.x;           // 1024
  const int bh = bid >> 5, qblk = bid & 31;
  const int t = threadIdx.x;
  const int q = qblk * 64 + (t >> 2);
  const int dp = (t & 3) * 16;
  const size_t base = (size_t)bh * 2048 + q;
  const size_t p1o = (size_t)32 * 2048;
  const float L0 = Lbuf[base];
  const float L1 = Lbuf[p1o + base];
  const float L = fmaxf(L0, L1);
  float w0 = ex2(L0 - L), w1 = ex2(L1 - L);
  const float rs = 1.f / (w0 + w1);
  w0 *= rs; w1 *= rs;
  const f16* p0 = opart + base * 64 + dp;
  const f16* p1 = opart + (p1o + base) * 64 + dp;
  f16x8 a0 = *(const f16x8*)p0, a1 = *(const f16x8*)(p0 + 8);
  f16x8 c0 = *(const f16x8*)p1, c1 = *(const f16x8*)(p1 + 8);
  f16x8 o0, o1;
#pragma unroll
  for (int j = 0; j < 8; j++) {
    o0[j] = (f16)(w0 * (float)a0[j] + w1 * (float)c0[j]);
    o1[j] = (f16)(w0 * (float)a1[j] + w1 * (float)c1[j]);
  }
  const int b = bh >> 4, h = bh & 15;
  f16* op = ctx + ((size_t)b * 2048 + q) * 1024 + h * 64 + dp;
  *(f16x8*)op = o0;
  *(f16x8*)(op + 8) = o1;
}

// ---------------------------------------------------------------------------
extern "C" void kernel_launch(void* const* d_in, const int* in_sizes, int n_in,
                              void* d_out, int out_size, void* d_ws, size_t ws_size,
                              hipStream_t stream) {
  const float* x   = (const float*)d_in[0];
  const float* pW1 = (const float*)d_in[1];
  const float* pb1 = (const float*)d_in[2];
  const float* pW2 = (const float*)d_in[3];
  const float* pb2 = (const float*)d_in[4];
  const float* gp  = (const float*)d_in[5];
  const float* bp  = (const float*)d_in[6];
  const float* Wq  = (const float*)d_in[7];
  const float* bq  = (const float*)d_in[8];
  const float* Wk  = (const float*)d_in[9];
  const float* bk  = (const float*)d_in[10];
  const float* Wv  = (const float*)d_in[11];
  const float* bv  = (const float*)d_in[12];
  const float* Wo  = (const float*)d_in[13];
  const float* bo  = (const float*)d_in[14];
  const float* g1  = (const float*)d_in[15];
  const float* b1  = (const float*)d_in[16];
  const float* Wf1 = (const float*)d_in[17];
  const float* bf1 = (const float*)d_in[18];
  const float* Wf2 = (const float*)d_in[19];
  const float* bf2 = (const float*)d_in[20];
  const float* g2  = (const float*)d_in[21];
  const float* b2  = (const float*)d_in[22];

  char* ws = (char*)d_ws;
  const size_t MB = 1024 * 1024;
  if (ws_size < 121 * MB) return;

  f16*   wtP1 = (f16*)(ws);              // [2048][1024]  4 MB
  f16*   wtP2 = (f16*)(ws + 4 * MB);     // [1024][2048]  4 MB
  f16*   wtQ  = (f16*)(ws + 8 * MB);     // [3072][1024]  6 MB fused qkv weights
  f16*   wtO  = (f16*)(ws + 14 * MB);    // [1024][1024]  2 MB
  f16*   wtF1 = (f16*)(ws + 16 * MB);    // [4096][1024]  8 MB
  f16*   wtF2 = (f16*)(ws + 24 * MB);    // [1024][4096]  8 MB
  f16*   big  = (f16*)(ws + 32 * MB);    // 32 MB: h1 / qk(24)+Vt(8) / f1
  f16*   xb   = (f16*)(ws + 64 * MB);    // 8 MB f16 x
  f16*   sb   = (f16*)(ws + 72 * MB);    // 8 MB s = LN1 out
  f16*   ybuf = (f16*)(ws + 80 * MB);    // 8 MB y = LN2 out
  f16*   ctx  = (f16*)(ws + 88 * MB);    // 8 MB attention output
  f16*   part = (f16*)(ws + 96 * MB);    // 16 MB split-K partials [2][4096][1024]
  f16*   opart= (f16*)(ws + 96 * MB);    // same region (disjoint lifetime)
  float* Lbuf = (float*)(ws + 112 * MB); // 0.5 MB [2][32][2048]
  float* bqkv = (float*)(ws + 112 * MB + 512 * 1024); // 12 KB
  f16*   wtK  = wtQ + (size_t)1024 * 1024;
  f16*   wtV  = wtQ + (size_t)2048 * 1024;
  f16*   Vt   = big + (size_t)4096 * 3072; // V^T [32 bh][64 d][2048 kv]

  dim3 blk(256);
  // one mega prep launch: cast + 9 wtrans + qkv bias
  prep_kernel<<<20492, blk, 0, stream>>>(x, xb, pW1, wtP1, pW2, wtP2,
                                         Wq, wtQ, Wk, wtK, Wv, wtV, Wo, wtO,
                                         Wf1, wtF1, Wf2, wtF2, bq, bk, bv, bqkv);

  // h1 = relu(x @ pW1 + pb1)            [4096][2048] f16 in big   (PF: 2/CU)
  gemm_kernel<1, true><<<512, blk, 0, stream>>>(xb, wtP1, pb1, big, nullptr, 2048, 1024, 16);
  // part = h1 @ pW2 (split-K), then LN1: s = LN(x + part0+part1 + pb2)
  gemm_splitk<<<512, blk, 0, stream>>>(big, wtP2, part, 2048);
  ln_res2<<<4096, blk, 0, stream>>>(part, xb, pb2, gp, bp, nullptr, sb);
  // qkv = s @ [Wq|Wk|Wv] + bias; Q,K normal (ld 3072), V transposed into Vt
  gemm_kernel<3, false><<<768, blk, 0, stream>>>(sb, wtQ, bqkv, big, Vt, 3072, 1024, 24);
  // attention partials (KV-split x2), then combine -> ctx f16
  attn_kernel<<<1024, blk, 0, stream>>>(big, big + 1024, Vt, opart, Lbuf, 3072);
  combine_kernel<<<1024, blk, 0, stream>>>(opart, Lbuf, ctx);
  // part = ctx @ Wo (split-K), then LN2: y = LN(s + part + bo)
  gemm_splitk<<<512, blk, 0, stream>>>(ctx, wtO, part, 1024);
  ln_res2<<<4096, blk, 0, stream>>>(part, sb, bo, g1, b1, nullptr, ybuf);
  // f1 = relu(y @ Wf1 + bf1)            [4096][4096] f16 in big   (4/CU: no PF)
  gemm_kernel<1, false><<<1024, blk, 0, stream>>>(ybuf, wtF1, bf1, big, nullptr, 4096, 1024, 32);
  // part = f1 @ Wf2 (split-K), then LN3 -> f32 d_out
  gemm_splitk<<<512, blk, 0, stream>>>(big, wtF2, part, 4096);
  ln_res2<<<4096, blk, 0, stream>>>(part, ybuf, bf2, g2, b2, (float*)d_out, nullptr);
}